// Round 1
// 1550.190 us; speedup vs baseline: 1.9152x; 1.9152x over previous
//
#include <hip/hip_runtime.h>
#include <math.h>

#define NNODES 50000
#define NEDGES 600000
#define DIM 128
#define GNSZ 5000
#define GESZ 60000
#define NDTOT (NNODES*DIM)
#define EPS_NORM 1e-5f
#define EPS_RED  1e-6f

union F4 { float4 v; float f[4]; };

__device__ __forceinline__ float4 ld4(const float* p){ return *(const float4*)p; }

// ---------------------------------------------------------------------------
// K1: node GEMMs.  Ah -> out_h (temporary), Bh/Dh/Eh -> ws.
// Block: 32 nodes x 128 outs, thread tile 4x4 (8 trow x 32 tcol).
// ---------------------------------------------------------------------------
__global__ __launch_bounds__(256) void k1_node_gemm(
    const float* __restrict__ h, const float* __restrict__ W, const float* __restrict__ bias,
    float* __restrict__ Ah, float* __restrict__ Bh, float* __restrict__ Dh, float* __restrict__ Eh)
{
  __shared__ float as[32][129];
  const int t = threadIdx.x;
  const int base = blockIdx.x * 32;
  #pragma unroll
  for (int i = 0; i < 4; i++){
    int f = t + i*256;
    int row = f >> 5, c4 = (f & 31) * 4;
    float4 v = make_float4(0.f,0.f,0.f,0.f);
    if (base + row < NNODES) v = ld4(h + (size_t)(base+row)*DIM + c4);
    as[row][c4+0]=v.x; as[row][c4+1]=v.y; as[row][c4+2]=v.z; as[row][c4+3]=v.w;
  }
  __syncthreads();
  const int tcol = t & 31, trow = t >> 5;
  float* outp[4] = {Ah, Bh, Dh, Eh};
  const int mats[4] = {0,1,3,4};
  #pragma unroll 1
  for (int mi = 0; mi < 4; mi++){
    const float* Wm = W + mats[mi]*(DIM*DIM);
    float acc[4][4];
    #pragma unroll
    for (int i=0;i<4;i++){
      #pragma unroll
      for (int j=0;j<4;j++) acc[i][j]=0.f;
    }
    #pragma unroll 4
    for (int k = 0; k < DIM; k++){
      F4 bv; bv.v = ld4(Wm + k*DIM + tcol*4);
      float a0 = as[trow*4+0][k], a1 = as[trow*4+1][k];
      float a2 = as[trow*4+2][k], a3 = as[trow*4+3][k];
      #pragma unroll
      for (int j=0;j<4;j++){
        acc[0][j] += a0*bv.f[j]; acc[1][j] += a1*bv.f[j];
        acc[2][j] += a2*bv.f[j]; acc[3][j] += a3*bv.f[j];
      }
    }
    F4 bb; bb.v = ld4(bias + mats[mi]*DIM + tcol*4);
    #pragma unroll
    for (int i=0;i<4;i++){
      int row = base + trow*4 + i;
      if (row < NNODES){
        F4 o;
        #pragma unroll
        for (int j=0;j<4;j++) o.f[j] = acc[i][j] + bb.f[j];
        *(float4*)(outp[mi] + (size_t)row*DIM + tcol*4) = o.v;
      }
    }
  }
}

// ---------------------------------------------------------------------------
// CSR build: in-degree histogram -> exclusive scan -> scatter edge ids.
// Replaces 153.6M float atomics in k2 with 1.2M int atomics here.
// ---------------------------------------------------------------------------
__global__ void k_hist(const int* __restrict__ dst, int* __restrict__ deg)
{
  int i = blockIdx.x*256 + threadIdx.x;
  if (i < NEDGES) atomicAdd(&deg[dst[i]], 1);
}

__global__ void k_scan(const int* __restrict__ deg, int* __restrict__ off)
{
  __shared__ int tot[256];
  const int t = threadIdx.x;
  const int CH = (NNODES + 255) / 256;   // 196
  const int base = t * CH;
  int s = 0;
  for (int k = 0; k < CH; k++){
    int i = base + k;
    if (i < NNODES) s += deg[i];
  }
  tot[t] = s;
  __syncthreads();
  // Hillis-Steele inclusive scan of per-thread totals
  for (int d = 1; d < 256; d <<= 1){
    int w = (t >= d) ? tot[t-d] : 0;
    __syncthreads();
    tot[t] += w;
    __syncthreads();
  }
  int run = tot[t] - s;                  // exclusive prefix for this chunk
  for (int k = 0; k < CH; k++){
    int i = base + k;
    if (i < NNODES){ off[i] = run; run += deg[i]; }
  }
  if (t == 255) off[NNODES] = run;       // == NEDGES
}

__global__ void k_scatter(const int* __restrict__ dst, const int* __restrict__ off,
                          int* __restrict__ cur, int* __restrict__ eidx)
{
  int i = blockIdx.x*256 + threadIdx.x;
  if (i < NEDGES){
    int d = dst[i];
    int p = atomicAdd(&cur[d], 1);
    eidx[off[d] + p] = i;
  }
}

// ---------------------------------------------------------------------------
// K2: edge GEMM only.  Ce + Dh[src] + Eh[dst] -> e_new, plus per-graph e-stats.
// No sigmoid, no Bh gather, no num/den atomics (moved to k_agg).
// 32 edges/block (divides 60000 -> block never straddles a graph).
// ---------------------------------------------------------------------------
__global__ __launch_bounds__(256) void k2_edge(
    const float* __restrict__ e, const int* __restrict__ src, const int* __restrict__ dst,
    const float* __restrict__ W, const float* __restrict__ bias,
    const float* __restrict__ Dh, const float* __restrict__ Eh,
    const float* __restrict__ snorm_e,
    float* __restrict__ e_new,
    float* __restrict__ sum_e, float* __restrict__ sumsq_e)
{
  __shared__ float as[32][129];
  __shared__ int ssrc[32], sdst[32];
  __shared__ float s_sum[128], s_sq[128];
  const int t = threadIdx.x;
  const int base = blockIdx.x * 32;
  if (t < 128){ s_sum[t]=0.f; s_sq[t]=0.f; }
  if (t >= 128 && t < 160) ssrc[t-128] = src[base + t - 128];
  if (t >= 160 && t < 192) sdst[t-160] = dst[base + t - 160];
  #pragma unroll
  for (int i = 0; i < 4; i++){
    int f = t + i*256;
    int row = f >> 5, c4 = (f & 31)*4;
    float4 v = ld4(e + (size_t)(base+row)*DIM + c4);
    as[row][c4+0]=v.x; as[row][c4+1]=v.y; as[row][c4+2]=v.z; as[row][c4+3]=v.w;
  }
  __syncthreads();
  const int tcol = t & 31, trow = t >> 5;
  const float* W2 = W + 2*(DIM*DIM);
  float acc[4][4];
  #pragma unroll
  for (int i=0;i<4;i++){
    #pragma unroll
    for (int j=0;j<4;j++) acc[i][j]=0.f;
  }
  #pragma unroll 4
  for (int k = 0; k < DIM; k++){
    F4 bv; bv.v = ld4(W2 + k*DIM + tcol*4);
    float a0 = as[trow*4+0][k], a1 = as[trow*4+1][k];
    float a2 = as[trow*4+2][k], a3 = as[trow*4+3][k];
    #pragma unroll
    for (int j=0;j<4;j++){
      acc[0][j] += a0*bv.f[j]; acc[1][j] += a1*bv.f[j];
      acc[2][j] += a2*bv.f[j]; acc[3][j] += a3*bv.f[j];
    }
  }
  F4 b2; b2.v = ld4(bias + 2*DIM + tcol*4);
  const float sn = snorm_e[0];
  float lsum[4] = {0,0,0,0}, lsq[4] = {0,0,0,0};
  #pragma unroll
  for (int i=0;i<4;i++){
    int el = trow*4 + i;
    int sgl = ssrc[el], dgl = sdst[el];
    F4 dh;  dh.v  = ld4(Dh + (size_t)sgl*DIM + tcol*4);
    F4 ehv; ehv.v = ld4(Eh + (size_t)dgl*DIM + tcol*4);
    F4 o;
    #pragma unroll
    for (int j=0;j<4;j++) o.f[j] = acc[i][j] + b2.f[j] + dh.f[j] + ehv.f[j];
    *(float4*)(e_new + (size_t)(base+el)*DIM + tcol*4) = o.v;
    #pragma unroll
    for (int j=0;j<4;j++){
      float x = o.f[j]*sn;
      lsum[j] += x; lsq[j] += x*x;
    }
  }
  #pragma unroll
  for (int j=0;j<4;j++){
    atomicAdd(&s_sum[tcol*4+j], lsum[j]);
    atomicAdd(&s_sq[tcol*4+j],  lsq[j]);
  }
  __syncthreads();
  if (t < 128){
    int g = base / GESZ;
    atomicAdd(&sum_e[g*DIM + t],  s_sum[t]);
    atomicAdd(&sumsq_e[g*DIM + t], s_sq[t]);
  }
}

// ---------------------------------------------------------------------------
// K_AGG (replaces k3 + the old atomics): per-node CSR aggregation.
// 32 lanes own one node's 128 dims; walk incoming edges, recompute sigmoid
// from stored e_new, accumulate num/den in registers.  Then
// h_pre = where(deg>0, Ah + num/(den+eps), h) * snorm_n  (in place in hbuf),
// plus per-graph h-stats.  8 nodes/block (divides 5000 -> no graph straddle).
// ---------------------------------------------------------------------------
__global__ __launch_bounds__(256) void k_agg(
    const float* __restrict__ h,
    const float* __restrict__ e_new,
    const float* __restrict__ Bh,
    const int* __restrict__ src,
    const int* __restrict__ off,
    const int* __restrict__ eidx,
    const float* __restrict__ snorm_n,
    float* hbuf,                       // in: Ah, out: h_pre (same memory)
    float* __restrict__ sum_h, float* __restrict__ sumsq_h)
{
  __shared__ float s_sum[128], s_sq[128];
  const int t = threadIdx.x;
  if (t < 128){ s_sum[t]=0.f; s_sq[t]=0.f; }
  __syncthreads();
  int idx4 = blockIdx.x*256 + t;
  int node = idx4 >> 5;
  int c4 = (idx4 & 31) * 4;
  size_t offp = (size_t)node*DIM + c4;
  const int beg = off[node], end = off[node+1];
  float num[4] = {0,0,0,0}, den[4] = {0,0,0,0};
  int eid = (beg < end) ? eidx[beg] : 0;
  for (int k = beg; k < end; k++){
    int eidn = (k+1 < end) ? eidx[k+1] : 0;   // prefetch next edge id
    int s = src[eid];
    F4 ev; ev.v = ld4(e_new + (size_t)eid*DIM + c4);
    F4 bh; bh.v = ld4(Bh + (size_t)s*DIM + c4);
    #pragma unroll
    for (int j=0;j<4;j++){
      float sig = 1.f/(1.f + __expf(-ev.f[j]));
      num[j] += sig * bh.f[j];
      den[j] += sig;
    }
    eid = eidn;
  }
  F4 a;  a.v  = *(float4*)(hbuf + offp);
  F4 hh; hh.v = ld4(h + offp);
  const float sn = snorm_n[0];
  const bool hasdeg = (end > beg);
  F4 x;
  #pragma unroll
  for (int j=0;j<4;j++){
    float v = hasdeg ? (a.f[j] + num[j]/(den[j] + EPS_RED)) : hh.f[j];
    x.f[j] = v * sn;
  }
  *(float4*)(hbuf + offp) = x.v;
  #pragma unroll
  for (int j=0;j<4;j++){
    atomicAdd(&s_sum[c4+j], x.f[j]);
    atomicAdd(&s_sq[c4+j],  x.f[j]*x.f[j]);
  }
  __syncthreads();
  if (t < 128){
    int g = (blockIdx.x*8) / GNSZ;
    atomicAdd(&sum_h[g*DIM+t],   s_sum[t]);
    atomicAdd(&sumsq_h[g*DIM+t], s_sq[t]);
  }
}

// ---------------------------------------------------------------------------
// K4: finalize mean / 1/(std+eps) for e and h stats.
// stats layout (floats): sum_e[0], sumsq_e[1280], sum_h[2560], sumsq_h[3840],
//                        mean_e[5120], inv_e[6400], mean_h[7680], inv_h[8960]
// ---------------------------------------------------------------------------
__global__ void k4_finalize(float* __restrict__ stats)
{
  int idx = blockIdx.x*256 + threadIdx.x;
  if (idx >= 2560) return;
  int which = idx / 1280;            // 0 = e, 1 = h
  int i = idx - which*1280;
  float n = which ? (float)GNSZ : (float)GESZ;
  float s  = stats[which*2560 + i];
  float sq = stats[which*2560 + 1280 + i];
  float mean = s / n;
  float var = (sq - s*s/n) / (n - 1.f);
  var = fmaxf(var, 0.f);
  float inv = 1.f / (sqrtf(var) + EPS_NORM);
  stats[5120 + which*2560 + i] = mean;
  stats[5120 + which*2560 + 1280 + i] = inv;
}

// ---------------------------------------------------------------------------
// K5h: out_h = h_in + relu(gamma*(h_pre - mean)*inv + beta), in place.
// ---------------------------------------------------------------------------
__global__ __launch_bounds__(256) void k5_norm_h(
    const float* __restrict__ h_in, const float* __restrict__ gamma, const float* __restrict__ beta,
    const float* __restrict__ stats, float* outp)
{
  int idx4 = blockIdx.x*256 + threadIdx.x;
  int node = idx4 >> 5;
  int c4 = (idx4 & 31)*4;
  int g = node / GNSZ;
  size_t off = (size_t)node*DIM + c4;
  F4 x;  x.v  = *(float4*)(outp + off);
  F4 mn; mn.v = ld4(stats + 7680 + g*DIM + c4);
  F4 iv; iv.v = ld4(stats + 8960 + g*DIM + c4);
  F4 gm; gm.v = ld4(gamma + c4);
  F4 bt; bt.v = ld4(beta + c4);
  F4 hi; hi.v = ld4(h_in + off);
  F4 o;
  #pragma unroll
  for (int j=0;j<4;j++){
    float y = gm.f[j]*((x.f[j]-mn.f[j])*iv.f[j]) + bt.f[j];
    o.f[j] = hi.f[j] + fmaxf(y, 0.f);
  }
  *(float4*)(outp + off) = o.v;
}

// ---------------------------------------------------------------------------
// K5e: out_e = e_in + relu(gamma*((e_new*sn - mean)*inv) + beta), in place.
// ---------------------------------------------------------------------------
__global__ __launch_bounds__(256) void k5_norm_e(
    const float* __restrict__ e_in, const float* __restrict__ gamma, const float* __restrict__ beta,
    const float* __restrict__ snorm_e, const float* __restrict__ stats, float* outp)
{
  int idx4 = blockIdx.x*256 + threadIdx.x;
  int edge = idx4 >> 5;
  int c4 = (idx4 & 31)*4;
  int g = edge / GESZ;
  size_t off = (size_t)edge*DIM + c4;
  const float sn = snorm_e[0];
  F4 x;  x.v  = *(float4*)(outp + off);
  F4 mn; mn.v = ld4(stats + 5120 + g*DIM + c4);
  F4 iv; iv.v = ld4(stats + 6400 + g*DIM + c4);
  F4 gm; gm.v = ld4(gamma + c4);
  F4 bt; bt.v = ld4(beta + c4);
  F4 ei; ei.v = ld4(e_in + off);
  F4 o;
  #pragma unroll
  for (int j=0;j<4;j++){
    float xx = x.f[j]*sn;
    float y = gm.f[j]*((xx-mn.f[j])*iv.f[j]) + bt.f[j];
    o.f[j] = ei.f[j] + fmaxf(y, 0.f);
  }
  *(float4*)(outp + off) = o.v;
}

extern "C" void kernel_launch(void* const* d_in, const int* in_sizes, int n_in,
                              void* d_out, int out_size, void* d_ws, size_t ws_size,
                              hipStream_t stream)
{
  (void)in_sizes; (void)n_in; (void)out_size; (void)ws_size;
  const float* h    = (const float*)d_in[0];
  const float* e    = (const float*)d_in[1];
  const int*   src  = (const int*)d_in[2];
  const int*   dst  = (const int*)d_in[3];
  const float* snorm_n = (const float*)d_in[4];
  const float* snorm_e = (const float*)d_in[5];
  const float* W    = (const float*)d_in[6];
  const float* bias = (const float*)d_in[7];
  const float* gamma_h = (const float*)d_in[8];
  const float* beta_h  = (const float*)d_in[9];
  const float* gamma_e = (const float*)d_in[10];
  const float* beta_e  = (const float*)d_in[11];

  float* out_h = (float*)d_out;                 // holds Ah, then h_pre, then h_new
  float* out_e = out_h + (size_t)NDTOT;         // holds e_new, then e_out
  float* ws  = (float*)d_ws;
  float* Bh  = ws;
  float* Dh  = ws + 1*(size_t)NDTOT;
  float* Eh  = ws + 2*(size_t)NDTOT;
  float* stats = ws + 3*(size_t)NDTOT;          // 10240 floats
  int* ints  = (int*)(stats + 10240);
  int* ideg  = ints;                            // N
  int* icur  = ints + NNODES;                   // N
  int* ioff  = ints + 2*NNODES;                 // N+1
  int* ieidx = ints + 3*NNODES + 1;             // E

  // zero sum/sumsq stats + deg + cursor (ws is poisoned before every launch)
  hipMemsetAsync(stats, 0, 5120*sizeof(float), stream);
  hipMemsetAsync(ints, 0, 2*(size_t)NNODES*sizeof(int), stream);

  // CSR build (cheap int atomics; independent of GEMMs)
  k_hist<<<(NEDGES+255)/256, 256, 0, stream>>>(dst, ideg);
  k_scan<<<1, 256, 0, stream>>>(ideg, ioff);
  k_scatter<<<(NEDGES+255)/256, 256, 0, stream>>>(dst, ioff, icur, ieidx);

  k1_node_gemm<<<1563, 256, 0, stream>>>(h, W, bias, out_h, Bh, Dh, Eh);
  k2_edge<<<18750, 256, 0, stream>>>(e, src, dst, W, bias, Dh, Eh, snorm_e,
                                     out_e, stats, stats+1280);
  k_agg<<<6250, 256, 0, stream>>>(h, out_e, Bh, src, ioff, ieidx, snorm_n,
                                  out_h, stats+2560, stats+3840);
  k4_finalize<<<10, 256, 0, stream>>>(stats);
  k5_norm_h<<<6250, 256, 0, stream>>>(h, gamma_h, beta_h, stats, out_h);
  k5_norm_e<<<75000, 256, 0, stream>>>(e, gamma_e, beta_e, snorm_e, stats, out_e);
}

// Round 3
// 1411.287 us; speedup vs baseline: 2.1037x; 1.0984x over previous
//
#include <hip/hip_runtime.h>
#include <math.h>

#define NNODES 50000
#define NEDGES 600000
#define DIM 128
#define GNSZ 5000
#define GESZ 60000
#define NDTOT (NNODES*DIM)
#define EPS_NORM 1e-5f
#define EPS_RED  1e-6f

union F4 { float4 v; float f[4]; };

__device__ __forceinline__ float4 ld4(const float* p){ return *(const float4*)p; }

typedef __attribute__((ext_vector_type(8))) short short8;
typedef __attribute__((ext_vector_type(4))) float f32x4;

union U8 { short8 v; unsigned short u[8]; };

// fp32 -> bf16 (RNE) and back, bit-level
__device__ __forceinline__ unsigned short f2bf(float x){
  unsigned u = __float_as_uint(x);
  u += 0x7FFFu + ((u >> 16) & 1u);
  return (unsigned short)(u >> 16);
}
__device__ __forceinline__ float bf2f(unsigned short b){
  return __uint_as_float(((unsigned)b) << 16);
}

// ---------------------------------------------------------------------------
// K0: pack W[5][128][128] fp32 into MFMA B-fragment order, split hi/lo bf16.
// Slot = ((mat*4+ks)*8+ct)*64+lane holds 8 bf16: W[k = ks*32+(lane>>4)*8+e]
// [col = ct*16+(lane&15)].  A-frags use the SAME slot->k convention, so the
// true HW k-permutation cancels (permutation invariance of the dot sum).
// ---------------------------------------------------------------------------
__global__ __launch_bounds__(256) void k0_pack(
    const float* __restrict__ W,
    unsigned short* __restrict__ Whi, unsigned short* __restrict__ Wlo)
{
  int slot = blockIdx.x*256 + threadIdx.x;    // 5*4*8*64 = 10240
  if (slot >= 10240) return;
  int lane = slot & 63;
  int ct   = (slot >> 6) & 7;
  int ks   = (slot >> 9) & 3;
  int mat  = slot >> 11;
  int g = lane >> 4;
  int col = ct*16 + (lane & 15);
  U8 ho, lo;
  #pragma unroll
  for (int e = 0; e < 8; e++){
    int k = ks*32 + g*8 + e;
    float x = W[mat*DIM*DIM + k*DIM + col];
    unsigned short hb = f2bf(x);
    ho.u[e] = hb;
    lo.u[e] = f2bf(x - bf2f(hb));
  }
  *(short8*)(Whi + (size_t)slot*8) = ho.v;
  *(short8*)(Wlo + (size_t)slot*8) = lo.v;
}

// ---------------------------------------------------------------------------
// K1: node GEMMs via MFMA split-bf16.  96 rows/block (6 waves x 16 rows).
// A frags loaded once (all 4 k-steps), reused across the 4 weight mats.
// ---------------------------------------------------------------------------
__global__ __launch_bounds__(384) void k1_node_gemm(
    const float* __restrict__ h,
    const unsigned short* __restrict__ Whi, const unsigned short* __restrict__ Wlo,
    const float* __restrict__ bias,
    float* __restrict__ Ah, float* __restrict__ Bh, float* __restrict__ Dh, float* __restrict__ Eh)
{
  const int t = threadIdx.x;
  const int w = t >> 6, l = t & 63;
  const int g = l >> 4, lr = l & 15;
  const int rbase = blockIdx.x*96 + w*16;
  const int rowA = rbase + lr;

  short8 ahi[4], alo[4];
  #pragma unroll
  for (int ks = 0; ks < 4; ks++){
    F4 q0, q1;
    if (rowA < NNODES){
      q0.v = ld4(h + (size_t)rowA*DIM + ks*32 + g*8);
      q1.v = ld4(h + (size_t)rowA*DIM + ks*32 + g*8 + 4);
    } else {
      q0.v = make_float4(0.f,0.f,0.f,0.f); q1.v = q0.v;
    }
    U8 ah, al;
    #pragma unroll
    for (int j = 0; j < 4; j++){
      unsigned short hb = f2bf(q0.f[j]);
      ah.u[j] = hb; al.u[j] = f2bf(q0.f[j] - bf2f(hb));
      hb = f2bf(q1.f[j]);
      ah.u[4+j] = hb; al.u[4+j] = f2bf(q1.f[j] - bf2f(hb));
    }
    ahi[ks] = ah.v; alo[ks] = al.v;
  }

  const int mats[4] = {0,1,3,4};
  float* outp[4] = {Ah, Bh, Dh, Eh};
  #pragma unroll 1
  for (int mi = 0; mi < 4; mi++){
    f32x4 acc[8];
    #pragma unroll
    for (int ct = 0; ct < 8; ct++) acc[ct] = (f32x4){0.f,0.f,0.f,0.f};
    #pragma unroll
    for (int ks = 0; ks < 4; ks++){
      const size_t fbase = (size_t)(mats[mi]*4 + ks)*4096 + (size_t)l*8;
      #pragma unroll
      for (int ct = 0; ct < 8; ct++){
        short8 bhi = *(const short8*)(Whi + fbase + ct*512);
        short8 blo = *(const short8*)(Wlo + fbase + ct*512);
        acc[ct] = __builtin_amdgcn_mfma_f32_16x16x32_bf16(ahi[ks], bhi, acc[ct], 0,0,0);
        acc[ct] = __builtin_amdgcn_mfma_f32_16x16x32_bf16(alo[ks], bhi, acc[ct], 0,0,0);
        acc[ct] = __builtin_amdgcn_mfma_f32_16x16x32_bf16(ahi[ks], blo, acc[ct], 0,0,0);
      }
    }
    const float* bb = bias + mats[mi]*DIM;
    #pragma unroll
    for (int r = 0; r < 4; r++){
      int row = rbase + g*4 + r;          // D: row=(lane>>4)*4+reg, col=lane&15 (m89)
      if (row < NNODES){
        float* op = outp[mi] + (size_t)row*DIM;
        #pragma unroll
        for (int ct = 0; ct < 8; ct++){
          int col = ct*16 + lr;
          op[col] = acc[ct][r] + bb[col];
        }
      }
    }
  }
}

// ---------------------------------------------------------------------------
// CSR build: in-degree histogram -> exclusive scan -> scatter edge ids.
// ---------------------------------------------------------------------------
__global__ void k_hist(const int* __restrict__ dst, int* __restrict__ deg)
{
  int i = blockIdx.x*256 + threadIdx.x;
  if (i < NEDGES) atomicAdd(&deg[dst[i]], 1);
}

__global__ void k_scan(const int* __restrict__ deg, int* __restrict__ off)
{
  __shared__ int tot[256];
  const int t = threadIdx.x;
  const int CH = (NNODES + 255) / 256;   // 196
  const int base = t * CH;
  int s = 0;
  for (int k = 0; k < CH; k++){
    int i = base + k;
    if (i < NNODES) s += deg[i];
  }
  tot[t] = s;
  __syncthreads();
  for (int d = 1; d < 256; d <<= 1){
    int wv = (t >= d) ? tot[t-d] : 0;
    __syncthreads();
    tot[t] += wv;
    __syncthreads();
  }
  int run = tot[t] - s;
  for (int k = 0; k < CH; k++){
    int i = base + k;
    if (i < NNODES){ off[i] = run; run += deg[i]; }
  }
  if (t == 255) off[NNODES] = run;
}

__global__ void k_scatter(const int* __restrict__ dst, const int* __restrict__ off,
                          int* __restrict__ cur, int* __restrict__ eidx)
{
  int i = blockIdx.x*256 + threadIdx.x;
  if (i < NEDGES){
    int d = dst[i];
    int p = atomicAdd(&cur[d], 1);
    eidx[off[d] + p] = i;
  }
}

// ---------------------------------------------------------------------------
// K2: edge GEMM via MFMA split-bf16 + gather Dh[src]+Eh[dst] + e-stats.
// 96 edges/block (6 waves x 16 edges); 96 | 60000 -> no graph straddle.
// ---------------------------------------------------------------------------
__global__ __launch_bounds__(384) void k2_edge(
    const float* __restrict__ e, const int* __restrict__ src, const int* __restrict__ dst,
    const unsigned short* __restrict__ Whi, const unsigned short* __restrict__ Wlo,
    const float* __restrict__ bias,
    const float* __restrict__ Dh, const float* __restrict__ Eh,
    const float* __restrict__ snorm_e,
    float* __restrict__ e_new,
    float* __restrict__ sum_e, float* __restrict__ sumsq_e)
{
  __shared__ int ssrc[96], sdst[96];
  __shared__ float s_sum[128], s_sq[128];
  const int t = threadIdx.x;
  const int base = blockIdx.x * 96;
  if (t < 96) ssrc[t] = src[base + t];
  else if (t < 192) sdst[t-96] = dst[base + t - 96];
  else if (t < 320){ s_sum[t-192] = 0.f; s_sq[t-192] = 0.f; }
  __syncthreads();

  const int w = t >> 6, l = t & 63, g = l >> 4, lr = l & 15;
  const int rowA = base + w*16 + lr;

  f32x4 acc[8];
  #pragma unroll
  for (int ct = 0; ct < 8; ct++) acc[ct] = (f32x4){0.f,0.f,0.f,0.f};

  #pragma unroll
  for (int ks = 0; ks < 4; ks++){
    F4 q0, q1;
    q0.v = ld4(e + (size_t)rowA*DIM + ks*32 + g*8);
    q1.v = ld4(e + (size_t)rowA*DIM + ks*32 + g*8 + 4);
    U8 ah, al;
    #pragma unroll
    for (int j = 0; j < 4; j++){
      unsigned short hb = f2bf(q0.f[j]);
      ah.u[j] = hb; al.u[j] = f2bf(q0.f[j] - bf2f(hb));
      hb = f2bf(q1.f[j]);
      ah.u[4+j] = hb; al.u[4+j] = f2bf(q1.f[j] - bf2f(hb));
    }
    const size_t fbase = (size_t)(2*4 + ks)*4096 + (size_t)l*8;   // mat 2
    #pragma unroll
    for (int ct = 0; ct < 8; ct++){
      short8 bhi = *(const short8*)(Whi + fbase + ct*512);
      short8 blo = *(const short8*)(Wlo + fbase + ct*512);
      acc[ct] = __builtin_amdgcn_mfma_f32_16x16x32_bf16(ah.v, bhi, acc[ct], 0,0,0);
      acc[ct] = __builtin_amdgcn_mfma_f32_16x16x32_bf16(al.v, bhi, acc[ct], 0,0,0);
      acc[ct] = __builtin_amdgcn_mfma_f32_16x16x32_bf16(ah.v, blo, acc[ct], 0,0,0);
    }
  }

  const float sn = snorm_e[0];
  const float* b2 = bias + 2*DIM;
  float lsum[8], lsq[8];
  #pragma unroll
  for (int ct = 0; ct < 8; ct++){ lsum[ct] = 0.f; lsq[ct] = 0.f; }

  #pragma unroll
  for (int r = 0; r < 4; r++){
    int erow = w*16 + g*4 + r;            // D-row mapping (m89)
    int edge = base + erow;
    int sgl = ssrc[erow], dgl = sdst[erow];
    const float* dp = Dh + (size_t)sgl*DIM;
    const float* ep = Eh + (size_t)dgl*DIM;
    float* op = e_new + (size_t)edge*DIM;
    #pragma unroll
    for (int ct = 0; ct < 8; ct++){
      int col = ct*16 + lr;
      float v = acc[ct][r] + b2[col] + dp[col] + ep[col];
      op[col] = v;
      float x = v*sn;
      lsum[ct] += x; lsq[ct] += x*x;
    }
  }
  #pragma unroll
  for (int ct = 0; ct < 8; ct++){
    atomicAdd(&s_sum[ct*16 + lr], lsum[ct]);
    atomicAdd(&s_sq[ct*16 + lr],  lsq[ct]);
  }
  __syncthreads();
  if (t < 128){
    int gg = base / GESZ;
    atomicAdd(&sum_e[gg*DIM + t],   s_sum[t]);
    atomicAdd(&sumsq_e[gg*DIM + t], s_sq[t]);
  }
}

// ---------------------------------------------------------------------------
// K_AGG: per-node CSR aggregation.
// ---------------------------------------------------------------------------
__global__ __launch_bounds__(256) void k_agg(
    const float* __restrict__ h,
    const float* __restrict__ e_new,
    const float* __restrict__ Bh,
    const int* __restrict__ src,
    const int* __restrict__ off,
    const int* __restrict__ eidx,
    const float* __restrict__ snorm_n,
    float* hbuf,
    float* __restrict__ sum_h, float* __restrict__ sumsq_h)
{
  __shared__ float s_sum[128], s_sq[128];
  const int t = threadIdx.x;
  if (t < 128){ s_sum[t]=0.f; s_sq[t]=0.f; }
  __syncthreads();
  int idx4 = blockIdx.x*256 + t;
  int node = idx4 >> 5;
  int c4 = (idx4 & 31) * 4;
  size_t offp = (size_t)node*DIM + c4;
  const int beg = off[node], end = off[node+1];
  float num[4] = {0,0,0,0}, den[4] = {0,0,0,0};
  int eid = (beg < end) ? eidx[beg] : 0;
  for (int k = beg; k < end; k++){
    int eidn = (k+1 < end) ? eidx[k+1] : 0;
    int s = src[eid];
    F4 ev; ev.v = ld4(e_new + (size_t)eid*DIM + c4);
    F4 bh; bh.v = ld4(Bh + (size_t)s*DIM + c4);
    #pragma unroll
    for (int j=0;j<4;j++){
      float sig = 1.f/(1.f + __expf(-ev.f[j]));
      num[j] += sig * bh.f[j];
      den[j] += sig;
    }
    eid = eidn;
  }
  F4 a;  a.v  = *(float4*)(hbuf + offp);
  F4 hh; hh.v = ld4(h + offp);
  const float sn = snorm_n[0];
  const bool hasdeg = (end > beg);
  F4 x;
  #pragma unroll
  for (int j=0;j<4;j++){
    float v = hasdeg ? (a.f[j] + num[j]/(den[j] + EPS_RED)) : hh.f[j];
    x.f[j] = v * sn;
  }
  *(float4*)(hbuf + offp) = x.v;
  #pragma unroll
  for (int j=0;j<4;j++){
    atomicAdd(&s_sum[c4+j], x.f[j]);
    atomicAdd(&s_sq[c4+j],  x.f[j]*x.f[j]);
  }
  __syncthreads();
  if (t < 128){
    int g = (blockIdx.x*8) / GNSZ;
    atomicAdd(&sum_h[g*DIM+t],   s_sum[t]);
    atomicAdd(&sumsq_h[g*DIM+t], s_sq[t]);
  }
}

// ---------------------------------------------------------------------------
// K4: finalize mean / 1/(std+eps).
// ---------------------------------------------------------------------------
__global__ void k4_finalize(float* __restrict__ stats)
{
  int idx = blockIdx.x*256 + threadIdx.x;
  if (idx >= 2560) return;
  int which = idx / 1280;
  int i = idx - which*1280;
  float n = which ? (float)GNSZ : (float)GESZ;
  float s  = stats[which*2560 + i];
  float sq = stats[which*2560 + 1280 + i];
  float mean = s / n;
  float var = (sq - s*s/n) / (n - 1.f);
  var = fmaxf(var, 0.f);
  float inv = 1.f / (sqrtf(var) + EPS_NORM);
  stats[5120 + which*2560 + i] = mean;
  stats[5120 + which*2560 + 1280 + i] = inv;
}

__global__ __launch_bounds__(256) void k5_norm_h(
    const float* __restrict__ h_in, const float* __restrict__ gamma, const float* __restrict__ beta,
    const float* __restrict__ stats, float* outp)
{
  int idx4 = blockIdx.x*256 + threadIdx.x;
  int node = idx4 >> 5;
  int c4 = (idx4 & 31)*4;
  int g = node / GNSZ;
  size_t off = (size_t)node*DIM + c4;
  F4 x;  x.v  = *(float4*)(outp + off);
  F4 mn; mn.v = ld4(stats + 7680 + g*DIM + c4);
  F4 iv; iv.v = ld4(stats + 8960 + g*DIM + c4);
  F4 gm; gm.v = ld4(gamma + c4);
  F4 bt; bt.v = ld4(beta + c4);
  F4 hi; hi.v = ld4(h_in + off);
  F4 o;
  #pragma unroll
  for (int j=0;j<4;j++){
    float y = gm.f[j]*((x.f[j]-mn.f[j])*iv.f[j]) + bt.f[j];
    o.f[j] = hi.f[j] + fmaxf(y, 0.f);
  }
  *(float4*)(outp + off) = o.v;
}

__global__ __launch_bounds__(256) void k5_norm_e(
    const float* __restrict__ e_in, const float* __restrict__ gamma, const float* __restrict__ beta,
    const float* __restrict__ snorm_e, const float* __restrict__ stats, float* outp)
{
  int idx4 = blockIdx.x*256 + threadIdx.x;
  int edge = idx4 >> 5;
  int c4 = (idx4 & 31)*4;
  int g = edge / GESZ;
  size_t off = (size_t)edge*DIM + c4;
  const float sn = snorm_e[0];
  F4 x;  x.v  = *(float4*)(outp + off);
  F4 mn; mn.v = ld4(stats + 5120 + g*DIM + c4);
  F4 iv; iv.v = ld4(stats + 6400 + g*DIM + c4);
  F4 gm; gm.v = ld4(gamma + c4);
  F4 bt; bt.v = ld4(beta + c4);
  F4 ei; ei.v = ld4(e_in + off);
  F4 o;
  #pragma unroll
  for (int j=0;j<4;j++){
    float xx = x.f[j]*sn;
    float y = gm.f[j]*((xx-mn.f[j])*iv.f[j]) + bt.f[j];
    o.f[j] = ei.f[j] + fmaxf(y, 0.f);
  }
  *(float4*)(outp + off) = o.v;
}

extern "C" void kernel_launch(void* const* d_in, const int* in_sizes, int n_in,
                              void* d_out, int out_size, void* d_ws, size_t ws_size,
                              hipStream_t stream)
{
  (void)in_sizes; (void)n_in; (void)out_size; (void)ws_size;
  const float* h    = (const float*)d_in[0];
  const float* e    = (const float*)d_in[1];
  const int*   src  = (const int*)d_in[2];
  const int*   dst  = (const int*)d_in[3];
  const float* snorm_n = (const float*)d_in[4];
  const float* snorm_e = (const float*)d_in[5];
  const float* W    = (const float*)d_in[6];
  const float* bias = (const float*)d_in[7];
  const float* gamma_h = (const float*)d_in[8];
  const float* beta_h  = (const float*)d_in[9];
  const float* gamma_e = (const float*)d_in[10];
  const float* beta_e  = (const float*)d_in[11];

  float* out_h = (float*)d_out;                 // Ah -> h_pre -> h_new
  float* out_e = out_h + (size_t)NDTOT;         // e_new -> e_out
  float* ws  = (float*)d_ws;
  float* Bh  = ws;
  float* Dh  = ws + 1*(size_t)NDTOT;
  float* Eh  = ws + 2*(size_t)NDTOT;
  float* stats = ws + 3*(size_t)NDTOT;          // 10240 floats
  unsigned short* Whi = (unsigned short*)(stats + 10240);   // 81920 ushorts
  unsigned short* Wlo = Whi + 81920;                        // 81920 ushorts
  int* ints  = (int*)(Wlo + 81920);
  int* ideg  = ints;                            // N
  int* icur  = ints + NNODES;                   // N
  int* ioff  = ints + 2*NNODES;                 // N+1
  int* ieidx = ints + 3*NNODES + 1;             // E

  hipMemsetAsync(stats, 0, 5120*sizeof(float), stream);
  hipMemsetAsync(ints, 0, 2*(size_t)NNODES*sizeof(int), stream);

  k0_pack<<<40, 256, 0, stream>>>(W, Whi, Wlo);
  k_hist<<<(NEDGES+255)/256, 256, 0, stream>>>(dst, ideg);
  k_scan<<<1, 256, 0, stream>>>(ideg, ioff);
  k_scatter<<<(NEDGES+255)/256, 256, 0, stream>>>(dst, ioff, icur, ieidx);

  k1_node_gemm<<<521, 384, 0, stream>>>(h, Whi, Wlo, bias, out_h, Bh, Dh, Eh);
  k2_edge<<<6250, 384, 0, stream>>>(e, src, dst, Whi, Wlo, bias, Dh, Eh, snorm_e,
                                    out_e, stats, stats+1280);
  k_agg<<<6250, 256, 0, stream>>>(h, out_e, Bh, src, ioff, ieidx, snorm_n,
                                  out_h, stats+2560, stats+3840);
  k4_finalize<<<10, 256, 0, stream>>>(stats);
  k5_norm_h<<<6250, 256, 0, stream>>>(h, gamma_h, beta_h, stats, out_h);
  k5_norm_e<<<75000, 256, 0, stream>>>(e, gamma_e, beta_e, snorm_e, stats, out_e);
}

// Round 4
// 1409.327 us; speedup vs baseline: 2.1066x; 1.0014x over previous
//
#include <hip/hip_runtime.h>
#include <math.h>

#define NNODES 50000
#define NEDGES 600000
#define DIM 128
#define GNSZ 5000
#define GESZ 60000
#define NDTOT (NNODES*DIM)
#define EPS_NORM 1e-5f
#define EPS_RED  1e-6f

union F4 { float4 v; float f[4]; };

__device__ __forceinline__ float4 ld4(const float* p){ return *(const float4*)p; }

typedef __attribute__((ext_vector_type(8))) short short8;
typedef __attribute__((ext_vector_type(4))) float f32x4;

union U8 { short8 v; unsigned short u[8]; };

// fp32 -> bf16 (RNE) and back, bit-level
__device__ __forceinline__ unsigned short f2bf(float x){
  unsigned u = __float_as_uint(x);
  u += 0x7FFFu + ((u >> 16) & 1u);
  return (unsigned short)(u >> 16);
}
__device__ __forceinline__ float bf2f(unsigned short b){
  return __uint_as_float(((unsigned)b) << 16);
}

// ---------------------------------------------------------------------------
// K0: pack W[5][128][128] fp32 into MFMA B-fragment order, split hi/lo bf16.
// Slot = ((mat*4+ks)*8+ct)*64+lane holds 8 bf16: W[k = ks*32+(lane>>4)*8+e]
// [col = ct*16+(lane&15)].  A-frags use the SAME slot->k convention, so the
// true HW k-permutation cancels (permutation invariance of the dot sum).
// ---------------------------------------------------------------------------
__global__ __launch_bounds__(256) void k0_pack(
    const float* __restrict__ W,
    unsigned short* __restrict__ Whi, unsigned short* __restrict__ Wlo)
{
  int slot = blockIdx.x*256 + threadIdx.x;    // 5*4*8*64 = 10240
  if (slot >= 10240) return;
  int lane = slot & 63;
  int ct   = (slot >> 6) & 7;
  int ks   = (slot >> 9) & 3;
  int mat  = slot >> 11;
  int g = lane >> 4;
  int col = ct*16 + (lane & 15);
  U8 ho, lo;
  #pragma unroll
  for (int e = 0; e < 8; e++){
    int k = ks*32 + g*8 + e;
    float x = W[mat*DIM*DIM + k*DIM + col];
    unsigned short hb = f2bf(x);
    ho.u[e] = hb;
    lo.u[e] = f2bf(x - bf2f(hb));
  }
  *(short8*)(Whi + (size_t)slot*8) = ho.v;
  *(short8*)(Wlo + (size_t)slot*8) = lo.v;
}

// ---------------------------------------------------------------------------
// K1: node GEMMs via MFMA split-bf16.  96 rows/block (6 waves x 16 rows).
// Epilogue: per-wave LDS transpose -> vectorized float4 stores.
// ---------------------------------------------------------------------------
__global__ __launch_bounds__(384) void k1_node_gemm(
    const float* __restrict__ h,
    const unsigned short* __restrict__ Whi, const unsigned short* __restrict__ Wlo,
    const float* __restrict__ bias,
    float* __restrict__ Ah, float* __restrict__ Bh, float* __restrict__ Dh, float* __restrict__ Eh)
{
  __shared__ float tbuf[6][16][132];          // per-wave 16x128 tile (+pad, 16B rows)
  const int t = threadIdx.x;
  const int w = t >> 6, l = t & 63;
  const int g = l >> 4, lr = l & 15;
  const int rbase = blockIdx.x*96 + w*16;
  const int rowA = rbase + lr;

  short8 ahi[4], alo[4];
  #pragma unroll
  for (int ks = 0; ks < 4; ks++){
    F4 q0, q1;
    if (rowA < NNODES){
      q0.v = ld4(h + (size_t)rowA*DIM + ks*32 + g*8);
      q1.v = ld4(h + (size_t)rowA*DIM + ks*32 + g*8 + 4);
    } else {
      q0.v = make_float4(0.f,0.f,0.f,0.f); q1.v = q0.v;
    }
    U8 ah, al;
    #pragma unroll
    for (int j = 0; j < 4; j++){
      unsigned short hb = f2bf(q0.f[j]);
      ah.u[j] = hb; al.u[j] = f2bf(q0.f[j] - bf2f(hb));
      hb = f2bf(q1.f[j]);
      ah.u[4+j] = hb; al.u[4+j] = f2bf(q1.f[j] - bf2f(hb));
    }
    ahi[ks] = ah.v; alo[ks] = al.v;
  }

  const int mats[4] = {0,1,3,4};
  float* outp[4] = {Ah, Bh, Dh, Eh};
  #pragma unroll 1
  for (int mi = 0; mi < 4; mi++){
    f32x4 acc[8];
    #pragma unroll
    for (int ct = 0; ct < 8; ct++) acc[ct] = (f32x4){0.f,0.f,0.f,0.f};
    #pragma unroll
    for (int ks = 0; ks < 4; ks++){
      const size_t fbase = (size_t)(mats[mi]*4 + ks)*4096 + (size_t)l*8;
      #pragma unroll
      for (int ct = 0; ct < 8; ct++){
        short8 bhi = *(const short8*)(Whi + fbase + ct*512);
        short8 blo = *(const short8*)(Wlo + fbase + ct*512);
        acc[ct] = __builtin_amdgcn_mfma_f32_16x16x32_bf16(ahi[ks], bhi, acc[ct], 0,0,0);
        acc[ct] = __builtin_amdgcn_mfma_f32_16x16x32_bf16(alo[ks], bhi, acc[ct], 0,0,0);
        acc[ct] = __builtin_amdgcn_mfma_f32_16x16x32_bf16(ahi[ks], blo, acc[ct], 0,0,0);
      }
    }
    // transpose: lane(g,lr) holds C[row=g*4+r][col=ct*16+lr]  (m89 layout)
    #pragma unroll
    for (int r = 0; r < 4; r++)
      #pragma unroll
      for (int ct = 0; ct < 8; ct++)
        tbuf[w][g*4+r][ct*16+lr] = acc[ct][r];
    // read back row-major: lane owns cols lr*8..lr*8+7 (same-wave RAW via LDS)
    F4 bb0, bb1;
    bb0.v = ld4(bias + mats[mi]*DIM + lr*8);
    bb1.v = ld4(bias + mats[mi]*DIM + lr*8 + 4);
    #pragma unroll
    for (int rb = 0; rb < 4; rb++){
      int row16 = rb*4 + g;
      int row = rbase + row16;
      if (row < NNODES){
        F4 t0, t1;
        t0.v = *(float4*)&tbuf[w][row16][lr*8];
        t1.v = *(float4*)&tbuf[w][row16][lr*8 + 4];
        F4 o0, o1;
        #pragma unroll
        for (int j = 0; j < 4; j++){ o0.f[j] = t0.f[j] + bb0.f[j]; o1.f[j] = t1.f[j] + bb1.f[j]; }
        float* op = outp[mi] + (size_t)row*DIM + lr*8;
        *(float4*)op = o0.v;
        *(float4*)(op + 4) = o1.v;
      }
    }
  }
}

// ---------------------------------------------------------------------------
// CSR build: in-degree histogram -> exclusive scan -> scatter edge ids.
// ---------------------------------------------------------------------------
__global__ void k_hist(const int* __restrict__ dst, int* __restrict__ deg)
{
  int i = blockIdx.x*256 + threadIdx.x;
  if (i < NEDGES) atomicAdd(&deg[dst[i]], 1);
}

__global__ void k_scan(const int* __restrict__ deg, int* __restrict__ off)
{
  __shared__ int tot[256];
  const int t = threadIdx.x;
  const int CH = (NNODES + 255) / 256;   // 196
  const int base = t * CH;
  int s = 0;
  for (int k = 0; k < CH; k++){
    int i = base + k;
    if (i < NNODES) s += deg[i];
  }
  tot[t] = s;
  __syncthreads();
  for (int d = 1; d < 256; d <<= 1){
    int wv = (t >= d) ? tot[t-d] : 0;
    __syncthreads();
    tot[t] += wv;
    __syncthreads();
  }
  int run = tot[t] - s;
  for (int k = 0; k < CH; k++){
    int i = base + k;
    if (i < NNODES){ off[i] = run; run += deg[i]; }
  }
  if (t == 255) off[NNODES] = run;
}

__global__ void k_scatter(const int* __restrict__ dst, const int* __restrict__ off,
                          int* __restrict__ cur, int* __restrict__ eidx)
{
  int i = blockIdx.x*256 + threadIdx.x;
  if (i < NEDGES){
    int d = dst[i];
    int p = atomicAdd(&cur[d], 1);
    eidx[off[d] + p] = i;
  }
}

// ---------------------------------------------------------------------------
// K2: edge GEMM via MFMA split-bf16 + gather Dh[src]+Eh[dst] + e-stats.
// 96 edges/block (6 waves x 16 edges); 96 | 60000 -> no graph straddle.
// Epilogue: per-wave LDS transpose -> float4 gathers/stores (was 96 scalar).
// ---------------------------------------------------------------------------
__global__ __launch_bounds__(384) void k2_edge(
    const float* __restrict__ e, const int* __restrict__ src, const int* __restrict__ dst,
    const unsigned short* __restrict__ Whi, const unsigned short* __restrict__ Wlo,
    const float* __restrict__ bias,
    const float* __restrict__ Dh, const float* __restrict__ Eh,
    const float* __restrict__ snorm_e,
    float* __restrict__ e_new,
    float* __restrict__ sum_e, float* __restrict__ sumsq_e)
{
  __shared__ float tbuf[6][16][132];
  __shared__ int ssrc[96], sdst[96];
  __shared__ float s_sum[128], s_sq[128];
  const int t = threadIdx.x;
  const int base = blockIdx.x * 96;
  if (t < 96) ssrc[t] = src[base + t];
  else if (t < 192) sdst[t-96] = dst[base + t - 96];
  else if (t < 320){ s_sum[t-192] = 0.f; s_sq[t-192] = 0.f; }
  __syncthreads();

  const int w = t >> 6, l = t & 63, g = l >> 4, lr = l & 15;
  const int rowA = base + w*16 + lr;

  f32x4 acc[8];
  #pragma unroll
  for (int ct = 0; ct < 8; ct++) acc[ct] = (f32x4){0.f,0.f,0.f,0.f};

  #pragma unroll
  for (int ks = 0; ks < 4; ks++){
    F4 q0, q1;
    q0.v = ld4(e + (size_t)rowA*DIM + ks*32 + g*8);
    q1.v = ld4(e + (size_t)rowA*DIM + ks*32 + g*8 + 4);
    U8 ah, al;
    #pragma unroll
    for (int j = 0; j < 4; j++){
      unsigned short hb = f2bf(q0.f[j]);
      ah.u[j] = hb; al.u[j] = f2bf(q0.f[j] - bf2f(hb));
      hb = f2bf(q1.f[j]);
      ah.u[4+j] = hb; al.u[4+j] = f2bf(q1.f[j] - bf2f(hb));
    }
    const size_t fbase = (size_t)(2*4 + ks)*4096 + (size_t)l*8;   // mat 2
    #pragma unroll
    for (int ct = 0; ct < 8; ct++){
      short8 bhi = *(const short8*)(Whi + fbase + ct*512);
      short8 blo = *(const short8*)(Wlo + fbase + ct*512);
      acc[ct] = __builtin_amdgcn_mfma_f32_16x16x32_bf16(ah.v, bhi, acc[ct], 0,0,0);
      acc[ct] = __builtin_amdgcn_mfma_f32_16x16x32_bf16(al.v, bhi, acc[ct], 0,0,0);
      acc[ct] = __builtin_amdgcn_mfma_f32_16x16x32_bf16(ah.v, blo, acc[ct], 0,0,0);
    }
  }

  // transpose to row-major in per-wave LDS slice (same-wave RAW, no barrier)
  #pragma unroll
  for (int r = 0; r < 4; r++)
    #pragma unroll
    for (int ct = 0; ct < 8; ct++)
      tbuf[w][g*4+r][ct*16+lr] = acc[ct][r];

  const float sn = snorm_e[0];
  F4 bb0, bb1;
  bb0.v = ld4(bias + 2*DIM + lr*8);
  bb1.v = ld4(bias + 2*DIM + lr*8 + 4);
  float lsum[8], lsq[8];
  #pragma unroll
  for (int j = 0; j < 8; j++){ lsum[j] = 0.f; lsq[j] = 0.f; }

  #pragma unroll
  for (int rb = 0; rb < 4; rb++){
    int row16 = rb*4 + g;
    int er = w*16 + row16;
    int edge = base + er;
    int sgl = ssrc[er], dgl = sdst[er];
    F4 t0, t1;
    t0.v = *(float4*)&tbuf[w][row16][lr*8];
    t1.v = *(float4*)&tbuf[w][row16][lr*8 + 4];
    F4 d0, d1, e0, e1;
    d0.v = ld4(Dh + (size_t)sgl*DIM + lr*8);
    d1.v = ld4(Dh + (size_t)sgl*DIM + lr*8 + 4);
    e0.v = ld4(Eh + (size_t)dgl*DIM + lr*8);
    e1.v = ld4(Eh + (size_t)dgl*DIM + lr*8 + 4);
    F4 o0, o1;
    #pragma unroll
    for (int j = 0; j < 4; j++){
      o0.f[j] = t0.f[j] + bb0.f[j] + d0.f[j] + e0.f[j];
      o1.f[j] = t1.f[j] + bb1.f[j] + d1.f[j] + e1.f[j];
      float x0 = o0.f[j]*sn, x1 = o1.f[j]*sn;
      lsum[j]   += x0; lsq[j]   += x0*x0;
      lsum[4+j] += x1; lsq[4+j] += x1*x1;
    }
    float* op = e_new + (size_t)edge*DIM + lr*8;
    *(float4*)op = o0.v;
    *(float4*)(op + 4) = o1.v;
  }
  #pragma unroll
  for (int j = 0; j < 8; j++){
    atomicAdd(&s_sum[lr*8 + j], lsum[j]);
    atomicAdd(&s_sq[lr*8 + j],  lsq[j]);
  }
  __syncthreads();
  if (t < 128){
    int gg = base / GESZ;
    atomicAdd(&sum_e[gg*DIM + t],   s_sum[t]);
    atomicAdd(&sumsq_e[gg*DIM + t], s_sq[t]);
  }
}

// ---------------------------------------------------------------------------
// K_AGG: per-node CSR aggregation, 4-way unrolled degree loop for MLP.
// ---------------------------------------------------------------------------
__global__ __launch_bounds__(256) void k_agg(
    const float* __restrict__ h,
    const float* __restrict__ e_new,
    const float* __restrict__ Bh,
    const int* __restrict__ src,
    const int* __restrict__ off,
    const int* __restrict__ eidx,
    const float* __restrict__ snorm_n,
    float* hbuf,
    float* __restrict__ sum_h, float* __restrict__ sumsq_h)
{
  __shared__ float s_sum[128], s_sq[128];
  const int t = threadIdx.x;
  if (t < 128){ s_sum[t]=0.f; s_sq[t]=0.f; }
  __syncthreads();
  int idx4 = blockIdx.x*256 + t;
  int node = idx4 >> 5;
  int c4 = (idx4 & 31) * 4;
  size_t offp = (size_t)node*DIM + c4;
  const int beg = off[node], end = off[node+1];
  float num[4] = {0,0,0,0}, den[4] = {0,0,0,0};
  int k = beg;
  for (; k + 4 <= end; k += 4){
    int e0 = eidx[k], e1 = eidx[k+1], e2 = eidx[k+2], e3 = eidx[k+3];
    int s0 = src[e0], s1 = src[e1], s2 = src[e2], s3 = src[e3];
    F4 v0, v1, v2, v3, b0, b1, b2, b3;
    v0.v = ld4(e_new + (size_t)e0*DIM + c4);
    v1.v = ld4(e_new + (size_t)e1*DIM + c4);
    v2.v = ld4(e_new + (size_t)e2*DIM + c4);
    v3.v = ld4(e_new + (size_t)e3*DIM + c4);
    b0.v = ld4(Bh + (size_t)s0*DIM + c4);
    b1.v = ld4(Bh + (size_t)s1*DIM + c4);
    b2.v = ld4(Bh + (size_t)s2*DIM + c4);
    b3.v = ld4(Bh + (size_t)s3*DIM + c4);
    #pragma unroll
    for (int j = 0; j < 4; j++){
      float g0 = 1.f/(1.f + __expf(-v0.f[j]));
      float g1 = 1.f/(1.f + __expf(-v1.f[j]));
      float g2 = 1.f/(1.f + __expf(-v2.f[j]));
      float g3 = 1.f/(1.f + __expf(-v3.f[j]));
      num[j] += g0*b0.f[j] + g1*b1.f[j] + g2*b2.f[j] + g3*b3.f[j];
      den[j] += g0 + g1 + g2 + g3;
    }
  }
  for (; k < end; k++){
    int e0 = eidx[k];
    int s0 = src[e0];
    F4 v0, b0;
    v0.v = ld4(e_new + (size_t)e0*DIM + c4);
    b0.v = ld4(Bh + (size_t)s0*DIM + c4);
    #pragma unroll
    for (int j = 0; j < 4; j++){
      float g0 = 1.f/(1.f + __expf(-v0.f[j]));
      num[j] += g0*b0.f[j];
      den[j] += g0;
    }
  }
  F4 a;  a.v  = *(float4*)(hbuf + offp);
  F4 hh; hh.v = ld4(h + offp);
  const float sn = snorm_n[0];
  const bool hasdeg = (end > beg);
  F4 x;
  #pragma unroll
  for (int j=0;j<4;j++){
    float v = hasdeg ? (a.f[j] + num[j]/(den[j] + EPS_RED)) : hh.f[j];
    x.f[j] = v * sn;
  }
  *(float4*)(hbuf + offp) = x.v;
  #pragma unroll
  for (int j=0;j<4;j++){
    atomicAdd(&s_sum[c4+j], x.f[j]);
    atomicAdd(&s_sq[c4+j],  x.f[j]*x.f[j]);
  }
  __syncthreads();
  if (t < 128){
    int g = (blockIdx.x*8) / GNSZ;
    atomicAdd(&sum_h[g*DIM+t],   s_sum[t]);
    atomicAdd(&sumsq_h[g*DIM+t], s_sq[t]);
  }
}

// ---------------------------------------------------------------------------
// K4: finalize mean / 1/(std+eps).
// ---------------------------------------------------------------------------
__global__ void k4_finalize(float* __restrict__ stats)
{
  int idx = blockIdx.x*256 + threadIdx.x;
  if (idx >= 2560) return;
  int which = idx / 1280;
  int i = idx - which*1280;
  float n = which ? (float)GNSZ : (float)GESZ;
  float s  = stats[which*2560 + i];
  float sq = stats[which*2560 + 1280 + i];
  float mean = s / n;
  float var = (sq - s*s/n) / (n - 1.f);
  var = fmaxf(var, 0.f);
  float inv = 1.f / (sqrtf(var) + EPS_NORM);
  stats[5120 + which*2560 + i] = mean;
  stats[5120 + which*2560 + 1280 + i] = inv;
}

__global__ __launch_bounds__(256) void k5_norm_h(
    const float* __restrict__ h_in, const float* __restrict__ gamma, const float* __restrict__ beta,
    const float* __restrict__ stats, float* outp)
{
  int idx4 = blockIdx.x*256 + threadIdx.x;
  int node = idx4 >> 5;
  int c4 = (idx4 & 31)*4;
  int g = node / GNSZ;
  size_t off = (size_t)node*DIM + c4;
  F4 x;  x.v  = *(float4*)(outp + off);
  F4 mn; mn.v = ld4(stats + 7680 + g*DIM + c4);
  F4 iv; iv.v = ld4(stats + 8960 + g*DIM + c4);
  F4 gm; gm.v = ld4(gamma + c4);
  F4 bt; bt.v = ld4(beta + c4);
  F4 hi; hi.v = ld4(h_in + off);
  F4 o;
  #pragma unroll
  for (int j=0;j<4;j++){
    float y = gm.f[j]*((x.f[j]-mn.f[j])*iv.f[j]) + bt.f[j];
    o.f[j] = hi.f[j] + fmaxf(y, 0.f);
  }
  *(float4*)(outp + off) = o.v;
}

__global__ __launch_bounds__(256) void k5_norm_e(
    const float* __restrict__ e_in, const float* __restrict__ gamma, const float* __restrict__ beta,
    const float* __restrict__ snorm_e, const float* __restrict__ stats, float* outp)
{
  int idx4 = blockIdx.x*256 + threadIdx.x;
  int edge = idx4 >> 5;
  int c4 = (idx4 & 31)*4;
  int g = edge / GESZ;
  size_t off = (size_t)edge*DIM + c4;
  const float sn = snorm_e[0];
  F4 x;  x.v  = *(float4*)(outp + off);
  F4 mn; mn.v = ld4(stats + 5120 + g*DIM + c4);
  F4 iv; iv.v = ld4(stats + 6400 + g*DIM + c4);
  F4 gm; gm.v = ld4(gamma + c4);
  F4 bt; bt.v = ld4(beta + c4);
  F4 ei; ei.v = ld4(e_in + off);
  F4 o;
  #pragma unroll
  for (int j=0;j<4;j++){
    float xx = x.f[j]*sn;
    float y = gm.f[j]*((xx-mn.f[j])*iv.f[j]) + bt.f[j];
    o.f[j] = ei.f[j] + fmaxf(y, 0.f);
  }
  *(float4*)(outp + off) = o.v;
}

extern "C" void kernel_launch(void* const* d_in, const int* in_sizes, int n_in,
                              void* d_out, int out_size, void* d_ws, size_t ws_size,
                              hipStream_t stream)
{
  (void)in_sizes; (void)n_in; (void)out_size; (void)ws_size;
  const float* h    = (const float*)d_in[0];
  const float* e    = (const float*)d_in[1];
  const int*   src  = (const int*)d_in[2];
  const int*   dst  = (const int*)d_in[3];
  const float* snorm_n = (const float*)d_in[4];
  const float* snorm_e = (const float*)d_in[5];
  const float* W    = (const float*)d_in[6];
  const float* bias = (const float*)d_in[7];
  const float* gamma_h = (const float*)d_in[8];
  const float* beta_h  = (const float*)d_in[9];
  const float* gamma_e = (const float*)d_in[10];
  const float* beta_e  = (const float*)d_in[11];

  float* out_h = (float*)d_out;                 // Ah -> h_pre -> h_new
  float* out_e = out_h + (size_t)NDTOT;         // e_new -> e_out
  float* ws  = (float*)d_ws;
  float* Bh  = ws;
  float* Dh  = ws + 1*(size_t)NDTOT;
  float* Eh  = ws + 2*(size_t)NDTOT;
  float* stats = ws + 3*(size_t)NDTOT;          // 10240 floats
  unsigned short* Whi = (unsigned short*)(stats + 10240);   // 81920 ushorts
  unsigned short* Wlo = Whi + 81920;                        // 81920 ushorts
  int* ints  = (int*)(Wlo + 81920);
  int* ideg  = ints;                            // N
  int* icur  = ints + NNODES;                   // N
  int* ioff  = ints + 2*NNODES;                 // N+1
  int* ieidx = ints + 3*NNODES + 1;             // E

  hipMemsetAsync(stats, 0, 5120*sizeof(float), stream);
  hipMemsetAsync(ints, 0, 2*(size_t)NNODES*sizeof(int), stream);

  k0_pack<<<40, 256, 0, stream>>>(W, Whi, Wlo);
  k_hist<<<(NEDGES+255)/256, 256, 0, stream>>>(dst, ideg);
  k_scan<<<1, 256, 0, stream>>>(ideg, ioff);
  k_scatter<<<(NEDGES+255)/256, 256, 0, stream>>>(dst, ioff, icur, ieidx);

  k1_node_gemm<<<521, 384, 0, stream>>>(h, Whi, Wlo, bias, out_h, Bh, Dh, Eh);
  k2_edge<<<6250, 384, 0, stream>>>(e, src, dst, Whi, Wlo, bias, Dh, Eh, snorm_e,
                                    out_e, stats, stats+1280);
  k_agg<<<6250, 256, 0, stream>>>(h, out_e, Bh, src, ioff, ieidx, snorm_n,
                                  out_h, stats+2560, stats+3840);
  k4_finalize<<<10, 256, 0, stream>>>(stats);
  k5_norm_h<<<6250, 256, 0, stream>>>(h, gamma_h, beta_h, stats, out_h);
  k5_norm_e<<<75000, 256, 0, stream>>>(e, gamma_e, beta_e, snorm_e, stats, out_e);
}